// Round 11
// baseline (299.481 us; speedup 1.0000x reference)
//
#include <hip/hip_runtime.h>
#include <hip/hip_bf16.h>
#include <hip/hip_fp16.h>
#include <math.h>

// ---------------- problem constants ----------------
constexpr int NN  = 32768;   // nodes
constexpr int BG  = 64;      // graphs
constexpr int NPG = 512;     // nodes per graph
constexpr int EG  = 524288;  // edges
constexpr int EPG = EG / BG; // 8192 edges per graph
constexpr int HH  = 4;       // heads
constexpr int FH  = 64;      // per-head dim
constexpr int CC  = 256;     // H*Fh
constexpr int FIN = 128;
constexpr int KP1 = 256;     // pool1 k
constexpr int KP2 = 128;     // pool2 k
constexpr int NS  = 4;       // register edge slots: fast path deg <= 64

typedef __attribute__((ext_vector_type(8))) short short8;  // 8 bf16 = 4 VGPRs
typedef __attribute__((ext_vector_type(4))) float f32x4;
typedef __attribute__((ext_vector_type(2))) float f32x2v;  // packed-fp32 pair

__device__ inline float leaky02(float v) { return v > 0.0f ? v : 0.2f * v; }

__device__ inline unsigned short f2bf(float v) {
    __hip_bfloat16 h = __float2bfloat16(v);
    return *(unsigned short*)&h;
}
__device__ inline float bf2f(unsigned short u) {
    __hip_bfloat16 h;
    *(unsigned short*)&h = u;
    return __bfloat162float(h);
}
__device__ inline void split2(float v, unsigned short& hi, unsigned short& lo) {
    hi = f2bf(v);
    lo = f2bf(v - bf2f(hi));
}
// split 8 consecutive floats into hi/lo bf16 fragments (A-operand order)
__device__ inline void split8(const float* p, short8& hi, short8& lo) {
    const float4 f0 = *(const float4*)p;
    const float4 f1 = *(const float4*)(p + 4);
    unsigned short h, l;
    split2(f0.x, h, l); hi[0] = (short)h; lo[0] = (short)l;
    split2(f0.y, h, l); hi[1] = (short)h; lo[1] = (short)l;
    split2(f0.z, h, l); hi[2] = (short)h; lo[2] = (short)l;
    split2(f0.w, h, l); hi[3] = (short)h; lo[3] = (short)l;
    split2(f1.x, h, l); hi[4] = (short)h; lo[4] = (short)l;
    split2(f1.y, h, l); hi[5] = (short)h; lo[5] = (short)l;
    split2(f1.z, h, l); hi[6] = (short)h; lo[6] = (short)l;
    split2(f1.w, h, l); hi[7] = (short)h; lo[7] = (short)l;
}

__device__ inline unsigned short f2h(float v) {
    __half h = __float2half(v);
    return *(unsigned short*)&h;
}
__device__ inline float h2f(unsigned short u) {
    __half h;
    *(unsigned short*)&h = u;
    return __half2float(h);
}

// monotone map: float ordering -> uint ordering (never returns 0 for non-NaN)
__device__ inline unsigned int fmap(float v) {
    unsigned int b = __float_as_uint(v);
    return (b & 0x80000000u) ? ~b : (b | 0x80000000u);
}

// accumulate a * row[0..7] (fp16) into 4 packed-f32 pairs (v_pk_fma_f32)
__device__ inline void acc8h(const unsigned short* p, float a, f32x2v* acc) {
    const uint4 u = *(const uint4*)p;
    const __half2* hp = (const __half2*)&u;
    f32x2v av; av[0] = a; av[1] = a;
#pragma unroll
    for (int i = 0; i < 4; ++i) {
        const float2 f = __half22float2(hp[i]);
        f32x2v fv; fv[0] = f.x; fv[1] = f.y;
        acc[i] = __builtin_elementwise_fma(fv, av, acc[i]);
    }
}

// ---------------- fused setup: csr_build + prep + W pack + x pack ---------
__global__ __launch_bounds__(1024) void setup_k(
        const int* __restrict__ src, const int* __restrict__ dst,
        int* __restrict__ rowp, int* __restrict__ esrc,
        const float* __restrict__ tw1, const float* __restrict__ sw2,
        const float* __restrict__ tb1, const float* __restrict__ sb2,
        float* __restrict__ w12, float* __restrict__ b12,
        const float* __restrict__ tw2, const float* __restrict__ c1w,
        const float* __restrict__ tb2, float* __restrict__ T,
        float* __restrict__ bc2,
        const float* __restrict__ W1, const float* __restrict__ W2,
        unsigned short* __restrict__ w1ph, unsigned short* __restrict__ w1pl,
        unsigned short* __restrict__ w2ph, unsigned short* __restrict__ w2pl,
        const float* __restrict__ x,
        unsigned short* __restrict__ xph, unsigned short* __restrict__ xpl) {
    __shared__ int lcnt[NPG];
    __shared__ int wsum[8];
    const int b = blockIdx.x;
    const int t = threadIdx.x;
    if (b < BG) {
        // ---- CSR build for graph b ----
        const int g = b;
        const int ebase = g * EPG;
        const int nbase = g * NPG;
        if (t < NPG) lcnt[t] = 0;
        __syncthreads();
        int ds[EPG / 1024];
#pragma unroll
        for (int j = 0; j < EPG / 1024; ++j) {
            ds[j] = dst[ebase + t + 1024 * j] - nbase;
            atomicAdd(&lcnt[ds[j]], 1);
        }
        __syncthreads();
        int c = 0, sInc = 0;
        if (t < NPG) {
            c = lcnt[t];
            sInc = c;
#pragma unroll
            for (int o = 1; o < 64; o <<= 1) {
                int v = __shfl_up(sInc, o);
                if ((t & 63) >= o) sInc += v;
            }
            if ((t & 63) == 63) wsum[t >> 6] = sInc;
        }
        __syncthreads();
        if (t < 8) {
            int v = wsum[t];
            int s = v;
#pragma unroll
            for (int o = 1; o < 8; o <<= 1) {
                int u2 = __shfl_up(s, o, 8);
                if (t >= o) s += u2;
            }
            wsum[t] = s - v;
        }
        __syncthreads();
        if (t < NPG) {
            const int ex = sInc - c + wsum[t >> 6];
            rowp[nbase + t] = ebase + ex;
            lcnt[t] = ex;
        }
        if (g == BG - 1 && t == 0) rowp[NN] = EG;
        __syncthreads();
#pragma unroll
        for (int j = 0; j < EPG / 1024; ++j) {
            int p = atomicAdd(&lcnt[ds[j]], 1);
            esrc[ebase + p] = src[ebase + t + 1024 * j];
        }
        return;
    }
    const int pb = b - BG;
    if (pb >= 114) {
        const size_t idx = ((size_t)(pb - 114) * 1024 + t) * 8;
        short8 hi, lo;
        split8(x + idx, hi, lo);
        *(short8*)(xph + idx) = hi;
        *(short8*)(xpl + idx) = lo;
        return;
    }
    if (t >= 256) return;
    if (pb < 66) {
        if (pb == 0) {
            float s = 0.0f;
            for (int o = 0; o < CC; ++o) s += tw1[t * CC + o] * sw2[o];
            w12[t] = s;
            if (t == 0) {
                float bb = 0.0f;
                for (int o = 0; o < CC; ++o) bb += tb1[o] * sw2[o];
                *b12 = bb + sb2[0];
            }
        } else if (pb < 65) {
            const int r = (pb - 1) * 4 + (t >> 6);
            const int cth = t & 63;
            float s = 0.0f;
            for (int j = 0; j < CC; ++j) s = fmaf(tw2[r * CC + j], c1w[j * 64 + cth], s);
            T[r * 64 + cth] = s;
        } else if (t < 64) {
            float s = 0.0f;
            for (int j = 0; j < CC; ++j) s = fmaf(tb2[j], c1w[j * 64 + t], s);
            bc2[t] = s;
        }
    } else {
        const int idx = (pb - 66) * 256 + t;   // 0..12287
        if (idx < 4096) {                      // W1
            const int nt = idx >> 8, rem = idx & 255;
            const int kg = rem >> 6, l = rem & 63;
            const int n = nt * 16 + (l & 15);
            const int kb = kg * 32 + (l >> 4) * 8;
            unsigned short h[8], lo[8];
#pragma unroll
            for (int j = 0; j < 8; ++j) split2(W1[(kb + j) * CC + n], h[j], lo[j]);
#pragma unroll
            for (int j = 0; j < 8; ++j) {
                w1ph[(size_t)idx * 8 + j] = h[j];
                w1pl[(size_t)idx * 8 + j] = lo[j];
            }
        } else {                               // W2
            const int i2 = idx - 4096;
            const int nt = i2 >> 9, rem = i2 & 511;
            const int kg = rem >> 6, l = rem & 63;
            const int n = nt * 16 + (l & 15);
            const int kb = kg * 32 + (l >> 4) * 8;
            unsigned short h[8], lo[8];
#pragma unroll
            for (int j = 0; j < 8; ++j) split2(W2[(kb + j) * CC + n], h[j], lo[j]);
#pragma unroll
            for (int j = 0; j < 8; ++j) {
                w2ph[(size_t)i2 * 8 + j] = h[j];
                w2pl[(size_t)i2 * 8 + j] = lo[j];
            }
        }
    }
}

// ---------------- MFMA GEMM (layer 1): A = packed split-bf16 pair ---------
__global__ __launch_bounds__(256, 4) void gemm_mfma_attn(
        const unsigned short* __restrict__ Ahi, const unsigned short* __restrict__ Alo,
        const unsigned short* __restrict__ Bph, const unsigned short* __restrict__ Bpl,
        unsigned short* __restrict__ Cb, int K,
        const float* __restrict__ a_src, const float* __restrict__ a_dst,
        float* __restrict__ es, float* __restrict__ ed,
        const float* __restrict__ tw1, const float* __restrict__ T,
        const float* __restrict__ tb1, const float* __restrict__ bc2,
        const float* __restrict__ c1b, float* __restrict__ Wc,
        float* __restrict__ bcv) {
    const int t = threadIdx.x;
    const int bx = blockIdx.x;
    if (bx >= NN / 32) {
        const int fb = bx - NN / 32;
        if (fb < 64) {
            const int r = fb * 4 + (t >> 6);
            const int cth = t & 63;
            float s = 0.0f;
            for (int j = 0; j < CC; ++j) s = fmaf(tw1[r * CC + j], T[j * 64 + cth], s);
            Wc[r * 64 + cth] = s;
        } else if (t < 64) {
            float s = 0.0f;
            for (int j = 0; j < CC; ++j) s = fmaf(tb1[j], T[j * 64 + t], s);
            bcv[t] = s + bc2[t] + c1b[t];
        }
        return;
    }
    const int w = t >> 6;
    const int l = t & 63;
    const int xcd  = bx & 7;
    const int slot = bx >> 3;
    const int gph  = xcd + ((slot >> 4) << 3);
    const int row0 = gph * NPG + ((slot & 15) << 5);
    const int m = l & 15;
    const int q = l >> 4;
    const int ncol0 = w * 64;
    const int KG = K >> 5;

    const unsigned short* aH0 = Ahi + (size_t)(row0 + m) * K + q * 8;
    const unsigned short* aL0 = Alo + (size_t)(row0 + m) * K + q * 8;
    const unsigned short* aH1 = aH0 + (size_t)16 * K;
    const unsigned short* aL1 = aL0 + (size_t)16 * K;

    f32x4 acc0[4], acc1[4];
#pragma unroll
    for (int c = 0; c < 4; ++c) {
        acc0[c] = (f32x4){0.f, 0.f, 0.f, 0.f};
        acc1[c] = (f32x4){0.f, 0.f, 0.f, 0.f};
    }

    for (int kg = 0; kg < KG; ++kg) {
        const int ko = kg * 32;
        short8 ah0 = *(const short8*)(aH0 + ko);
        short8 al0 = *(const short8*)(aL0 + ko);
        short8 ah1 = *(const short8*)(aH1 + ko);
        short8 al1 = *(const short8*)(aL1 + ko);
#pragma unroll
        for (int c = 0; c < 4; ++c) {
            const int nt = (w << 2) + c;
            const size_t boff = ((size_t)(nt * KG + kg) * 64 + l) * 8;
            short8 bh = *(const short8*)(Bph + boff);
            short8 bl = *(const short8*)(Bpl + boff);
            acc0[c] = __builtin_amdgcn_mfma_f32_16x16x32_bf16(ah0, bh, acc0[c], 0, 0, 0);
            acc0[c] = __builtin_amdgcn_mfma_f32_16x16x32_bf16(ah0, bl, acc0[c], 0, 0, 0);
            acc0[c] = __builtin_amdgcn_mfma_f32_16x16x32_bf16(al0, bh, acc0[c], 0, 0, 0);
            acc1[c] = __builtin_amdgcn_mfma_f32_16x16x32_bf16(ah1, bh, acc1[c], 0, 0, 0);
            acc1[c] = __builtin_amdgcn_mfma_f32_16x16x32_bf16(ah1, bl, acc1[c], 0, 0, 0);
            acc1[c] = __builtin_amdgcn_mfma_f32_16x16x32_bf16(al1, bh, acc1[c], 0, 0, 0);
        }
    }

#pragma unroll
    for (int c = 0; c < 4; ++c)
#pragma unroll
        for (int r = 0; r < 4; ++r) {
            Cb[(size_t)(row0 + q * 4 + r) * CC + ncol0 + c * 16 + m] = f2h(acc0[c][r]);
            Cb[(size_t)(row0 + 16 + q * 4 + r) * CC + ncol0 + c * 16 + m] = f2h(acc1[c][r]);
        }

    float asv[4], adv[4];
#pragma unroll
    for (int c = 0; c < 4; ++c) {
        asv[c] = a_src[ncol0 + c * 16 + m];
        adv[c] = a_dst[ncol0 + c * 16 + m];
    }
#pragma unroll
    for (int r = 0; r < 4; ++r) {
        float ps0 = 0.f, pd0 = 0.f, ps1 = 0.f, pd1 = 0.f;
#pragma unroll
        for (int c = 0; c < 4; ++c) {
            ps0 = fmaf(acc0[c][r], asv[c], ps0);
            pd0 = fmaf(acc0[c][r], adv[c], pd0);
            ps1 = fmaf(acc1[c][r], asv[c], ps1);
            pd1 = fmaf(acc1[c][r], adv[c], pd1);
        }
#pragma unroll
        for (int o = 8; o >= 1; o >>= 1) {
            ps0 += __shfl_down(ps0, o, 16);
            pd0 += __shfl_down(pd0, o, 16);
            ps1 += __shfl_down(ps1, o, 16);
            pd1 += __shfl_down(pd1, o, 16);
        }
        if (m == 0) {
            es[(row0 + q * 4 + r) * HH + w] = ps0;
            ed[(row0 + q * 4 + r) * HH + w] = pd0;
            es[(row0 + 16 + q * 4 + r) * HH + w] = ps1;
            ed[(row0 + 16 + q * 4 + r) * HH + w] = pd1;
        }
    }
}

// ---------------- fused edge1 + gemm2: one block = 32 nodes ---------------
// Phase A unchanged (register gather of fp16 zh1 rows). Phase B epilogue now
// writes zh2 in B-FRAGMENT-PACKED split-bf16 layout (consumed by spmm_edge2):
// per graph, [nt 0..15][kg 0..15][lane 0..63][j 0..7], k=kg*32+(l>>4)*8+j,
// n=nt*16+(l&15).
__global__ __launch_bounds__(256) void edge1_gemm2(
        const unsigned short* __restrict__ zh1,
        const int* __restrict__ rowp, const int* __restrict__ esrc,
        const float* __restrict__ es1, const float* __restrict__ ed1,
        const float* __restrict__ bias,
        const unsigned short* __restrict__ Bph, const unsigned short* __restrict__ Bpl,
        unsigned short* __restrict__ zh2ph, unsigned short* __restrict__ zh2pl,
        const float* __restrict__ a_src, const float* __restrict__ a_dst,
        float* __restrict__ es2, float* __restrict__ ed2) {
    __shared__ unsigned char AhB[32 * 512];
    __shared__ unsigned char AlB[32 * 512];
    const int t = threadIdx.x;
    const int w = t >> 6;
    const int l = t & 63;
    const int bx   = blockIdx.x;               // 0..1023
    const int xcd  = bx & 7;
    const int slot = bx >> 3;
    const int gph  = xcd + ((slot >> 4) << 3);
    const int row0 = gph * NPG + ((slot & 15) << 5);

    const int h    = l & 3;
    const int ei   = l >> 2;
    const int lh   = l & 31;
    const int half = l >> 5;
    const int hcol = lh >> 3;
    const int c0   = lh << 3;

    for (int nd = 0; nd < 8; ++nd) {
        const int rloc = w * 8 + nd;           // 0..31
        const int d = row0 + rloc;
        const int beg = rowp[d];
        const int deg = rowp[d + 1] - beg;

        f32x2v acc[4];
#pragma unroll
        for (int i = 0; i < 4; ++i) acc[i] = (f32x2v){0.f, 0.f};

        if (deg <= 16 * NS) {
            const float edh = ed1[d * HH + h];
            int   sidx[NS];
            float v[NS];
#pragma unroll
            for (int j = 0; j < NS; ++j) { sidx[j] = d; v[j] = 0.0f; }
            float vmax = -INFINITY, eself = 0.0f, vself = 0.0f;
            if (ei == 0) {
                vself = leaky02(es1[d * HH + h] + edh);
                vmax = vself;
            }
#pragma unroll
            for (int j = 0; j < NS; ++j) {
                int i = ei + 16 * j;
                if (i < deg) {
                    sidx[j] = esrc[beg + i];
                    v[j] = leaky02(es1[sidx[j] * HH + h] + edh);
                    vmax = fmaxf(vmax, v[j]);
                }
            }
#pragma unroll
            for (int o = 4; o <= 32; o <<= 1) vmax = fmaxf(vmax, __shfl_xor(vmax, o));
            float dsum = 0.0f;
#pragma unroll
            for (int j = 0; j < NS; ++j) {
                int i = ei + 16 * j;
                if (i < deg) { v[j] = __expf(v[j] - vmax); dsum += v[j]; }
            }
            if (ei == 0) { eself = __expf(vself - vmax); dsum += eself; }
#pragma unroll
            for (int o = 4; o <= 32; o <<= 1) dsum += __shfl_xor(dsum, o);
            const float inv = 1.0f / (dsum + 1e-16f);
#pragma unroll
            for (int j = 0; j < NS; ++j) v[j] *= inv;
            eself *= inv;

            float aself = __shfl(eself, hcol);
            if (half) aself = 0.0f;
            acc8h(zh1 + (size_t)d * CC + c0, aself, acc);

#pragma unroll
            for (int j = 0; j < NS; ++j) {
                if (16 * j < deg) {
#pragma unroll
                    for (int rr = 0; rr < 8; ++rr) {
                        if (16 * j + 2 * rr < deg) {
                            const int slb  = (2 * rr + half) << 2;
                            const int srcn = __shfl(sidx[j], slb);
                            const float a  = __shfl(v[j], slb + hcol);
                            acc8h(zh1 + (size_t)srcn * CC + c0, a, acc);
                        }
                    }
                }
            }
        } else {
            const float edh = ed1[d * HH + h];
            float vmax = (ei == 0) ? leaky02(es1[d * HH + h] + edh) : -INFINITY;
            for (int i = ei; i < deg; i += 16)
                vmax = fmaxf(vmax, leaky02(es1[esrc[beg + i] * HH + h] + edh));
#pragma unroll
            for (int o = 4; o <= 32; o <<= 1) vmax = fmaxf(vmax, __shfl_xor(vmax, o));
            float dsum = (ei == 0) ? __expf(leaky02(es1[d * HH + h] + edh) - vmax) : 0.0f;
            for (int i = ei; i < deg; i += 16)
                dsum += __expf(leaky02(es1[esrc[beg + i] * HH + h] + edh) - vmax);
#pragma unroll
            for (int o = 4; o <= 32; o <<= 1) dsum += __shfl_xor(dsum, o);
            const float inv = 1.0f / (dsum + 1e-16f);

            const float vmaxc = __shfl(vmax, hcol);
            const float invc  = __shfl(inv,  hcol);
            const float edh4  = ed1[d * HH + hcol];
            float a0 = __expf(leaky02(es1[d * HH + hcol] + edh4) - vmaxc) * invc;
            if (half) a0 = 0.0f;
            acc8h(zh1 + (size_t)d * CC + c0, a0, acc);
            for (int e = half; e < deg; e += 2) {
                const int srcn = esrc[beg + e];
                const float a = __expf(leaky02(es1[srcn * HH + hcol] + edh4) - vmaxc) * invc;
                acc8h(zh1 + (size_t)srcn * CC + c0, a, acc);
            }
        }

#pragma unroll
        for (int i = 0; i < 4; ++i) {
            float a0 = acc[i][0]; a0 += __shfl_xor(a0, 32);
            float a1 = acc[i][1]; a1 += __shfl_xor(a1, 32);
            acc[i][0] = a0; acc[i][1] = a1;
        }

        const int cw = c0 + (half << 2);
        float o0 = half ? acc[2][0] : acc[0][0];
        float o1 = half ? acc[2][1] : acc[0][1];
        float o2 = half ? acc[3][0] : acc[1][0];
        float o3 = half ? acc[3][1] : acc[1][1];

        const float4 bv = *(const float4*)(bias + cw);
        o0 += bv.x; o0 = o0 > 0.0f ? o0 : __expf(o0) - 1.0f;
        o1 += bv.y; o1 = o1 > 0.0f ? o1 : __expf(o1) - 1.0f;
        o2 += bv.z; o2 = o2 > 0.0f ? o2 : __expf(o2) - 1.0f;
        o3 += bv.w; o3 = o3 > 0.0f ? o3 : __expf(o3) - 1.0f;

        ushort4 uh, ul;
        split2(o0, uh.x, ul.x);
        split2(o1, uh.y, ul.y);
        split2(o2, uh.z, ul.z);
        split2(o3, uh.w, ul.w);
        const size_t bo = (size_t)(((rloc * 512) + cw * 2) ^ ((rloc & 7) << 4));
        *(ushort4*)(AhB + bo) = uh;
        *(ushort4*)(AlB + bo) = ul;
    }

    __syncthreads();

    // ---- phase B: 32x256 GEMM, K=256, A from swizzled LDS ----
    const int m = l & 15;
    const int q = l >> 4;
    const int ncol0 = w * 64;
    constexpr int KG = CC >> 5;   // 8

    f32x4 acc0[4], acc1[4];
#pragma unroll
    for (int c = 0; c < 4; ++c) {
        acc0[c] = (f32x4){0.f, 0.f, 0.f, 0.f};
        acc1[c] = (f32x4){0.f, 0.f, 0.f, 0.f};
    }

    for (int kg = 0; kg < KG; ++kg) {
        const int co = kg * 64 + q * 16;      // byte col offset
        const size_t bo0 = (size_t)(((m * 512) + co) ^ ((m & 7) << 4));
        const size_t bo1 = (size_t)((((16 + m) * 512) + co) ^ ((m & 7) << 4));
        short8 ah0 = *(const short8*)(AhB + bo0);
        short8 al0 = *(const short8*)(AlB + bo0);
        short8 ah1 = *(const short8*)(AhB + bo1);
        short8 al1 = *(const short8*)(AlB + bo1);
#pragma unroll
        for (int c = 0; c < 4; ++c) {
            const int nt = (w << 2) + c;
            const size_t boff = ((size_t)(nt * KG + kg) * 64 + l) * 8;
            short8 bh = *(const short8*)(Bph + boff);
            short8 bl = *(const short8*)(Bpl + boff);
            acc0[c] = __builtin_amdgcn_mfma_f32_16x16x32_bf16(ah0, bh, acc0[c], 0, 0, 0);
            acc0[c] = __builtin_amdgcn_mfma_f32_16x16x32_bf16(ah0, bl, acc0[c], 0, 0, 0);
            acc0[c] = __builtin_amdgcn_mfma_f32_16x16x32_bf16(al0, bh, acc0[c], 0, 0, 0);
            acc1[c] = __builtin_amdgcn_mfma_f32_16x16x32_bf16(ah1, bh, acc1[c], 0, 0, 0);
            acc1[c] = __builtin_amdgcn_mfma_f32_16x16x32_bf16(ah1, bl, acc1[c], 0, 0, 0);
            acc1[c] = __builtin_amdgcn_mfma_f32_16x16x32_bf16(al1, bh, acc1[c], 0, 0, 0);
        }
    }

    // ---- C-write: B-fragment-packed split-bf16 zh2 ----
    {
        const int kgB = slot & 15;     // rows row0..row0+31 => rl = kgB*32 + r32
        const size_t gb2 = (size_t)gph * 131072;   // 16*16*64*8
#pragma unroll
        for (int c = 0; c < 4; ++c) {
            const int nt = (w << 2) + c;
            const size_t ntb = gb2 + (size_t)(nt * 16 + kgB) * 512;  // *64*8
#pragma unroll
            for (int r = 0; r < 4; ++r) {
                unsigned short hh, ll;
                const int r32a = q * 4 + r;                // 0..15
                const int lpa  = ((r32a >> 3) << 4) | m;
                const size_t offa = ntb + (size_t)lpa * 8 + (r32a & 7);
                split2(acc0[c][r], hh, ll);
                zh2ph[offa] = hh; zh2pl[offa] = ll;
                const int r32b = 16 + q * 4 + r;           // 16..31
                const int lpb  = ((r32b >> 3) << 4) | m;
                const size_t offb = ntb + (size_t)lpb * 8 + (r32b & 7);
                split2(acc1[c][r], hh, ll);
                zh2ph[offb] = hh; zh2pl[offb] = ll;
            }
        }
    }

    float asv[4], adv[4];
#pragma unroll
    for (int c = 0; c < 4; ++c) {
        asv[c] = a_src[ncol0 + c * 16 + m];
        adv[c] = a_dst[ncol0 + c * 16 + m];
    }
#pragma unroll
    for (int r = 0; r < 4; ++r) {
        float ps0 = 0.f, pd0 = 0.f, ps1 = 0.f, pd1 = 0.f;
#pragma unroll
        for (int c = 0; c < 4; ++c) {
            ps0 = fmaf(acc0[c][r], asv[c], ps0);
            pd0 = fmaf(acc0[c][r], adv[c], pd0);
            ps1 = fmaf(acc1[c][r], asv[c], ps1);
            pd1 = fmaf(acc1[c][r], adv[c], pd1);
        }
#pragma unroll
        for (int o = 8; o >= 1; o >>= 1) {
            ps0 += __shfl_down(ps0, o, 16);
            pd0 += __shfl_down(pd0, o, 16);
            ps1 += __shfl_down(ps1, o, 16);
            pd1 += __shfl_down(pd1, o, 16);
        }
        if (m == 0) {
            es2[(row0 + q * 4 + r) * HH + w] = ps0;
            ed2[(row0 + q * 4 + r) * HH + w] = pd0;
            es2[(row0 + 16 + q * 4 + r) * HH + w] = ps1;
            ed2[(row0 + 16 + q * 4 + r) * HH + w] = pd1;
        }
    }
}

// ---------------- layer-2 edge stage as dense SpMM on matrix cores --------
// Block = 32 dst rows, 4 waves (wave = head). Per 64-src chunk: scatter
// fp32 alpha into LDS A-tile (atomicAdd handles duplicate edges), then
// split-bf16 MFMA against fragment-packed zh2. Epilogue: bias+ELU, fp16
// featH, fused sc1/sc2 score reductions.
__global__ __launch_bounds__(256) void spmm_edge2(
        const int* __restrict__ rowp, const int* __restrict__ esrc,
        const float* __restrict__ es, const float* __restrict__ ed,
        const float* __restrict__ bias,
        const unsigned short* __restrict__ Bph, const unsigned short* __restrict__ Bpl,
        unsigned short* __restrict__ featH,
        const float* __restrict__ sw1, const float* __restrict__ sb1,
        const float* __restrict__ w12, const float* __restrict__ b12,
        float* __restrict__ sc1, float* __restrict__ sc2) {
    __shared__ float Af[4][32][64];            // 32 KB alpha chunk
    __shared__ float vmL[32][4], invL[32][4], aslL[32][4], edhL[32][4];
    __shared__ float scp1[4][32], scp2[4][32];
    const int t = threadIdx.x;
    const int w = t >> 6;          // wave = head
    const int l = t & 63;
    const int bx   = blockIdx.x;
    const int xcd  = bx & 7;
    const int slot = bx >> 3;
    const int gph  = xcd + ((slot >> 4) << 3);
    const int row0 = gph * NPG + ((slot & 15) << 5);
    const int rbase = (slot & 15) << 5;        // row-within-graph base
    const int gbase = gph * NPG;

    const int h  = l & 3;
    const int ei = l >> 2;

    // ---- phase 0: per-node softmax stats ----
    for (int nd = 0; nd < 8; ++nd) {
        const int rloc = w * 8 + nd;
        const int d = row0 + rloc;
        const int beg = rowp[d];
        const int deg = rowp[d + 1] - beg;
        const float edh = ed[d * HH + h];
        const float vself = leaky02(es[d * HH + h] + edh);
        float vmax = (ei == 0) ? vself : -INFINITY;
        for (int i = ei; i < deg; i += 16)
            vmax = fmaxf(vmax, leaky02(es[esrc[beg + i] * HH + h] + edh));
#pragma unroll
        for (int o = 4; o <= 32; o <<= 1) vmax = fmaxf(vmax, __shfl_xor(vmax, o));
        float dsum = (ei == 0) ? __expf(vself - vmax) : 0.0f;
        for (int i = ei; i < deg; i += 16)
            dsum += __expf(leaky02(es[esrc[beg + i] * HH + h] + edh) - vmax);
#pragma unroll
        for (int o = 4; o <= 32; o <<= 1) dsum += __shfl_xor(dsum, o);
        const float inv = 1.0f / (dsum + 1e-16f);
        if (ei == 0) {
            vmL[rloc][h]  = vmax;
            invL[rloc][h] = inv;
            aslL[rloc][h] = __expf(vself - vmax) * inv;
            edhL[rloc][h] = edh;
        }
    }

    const int m = l & 15;
    const int q = l >> 4;
    const int ncol0 = w * 64;
    const size_t gb2 = (size_t)gph * 131072;

    f32x4 acc0[4], acc1[4];
#pragma unroll
    for (int c = 0; c < 4; ++c) {
        acc0[c] = (f32x4){0.f, 0.f, 0.f, 0.f};
        acc1[c] = (f32x4){0.f, 0.f, 0.f, 0.f};
    }

    for (int ck = 0; ck < 8; ++ck) {
        __syncthreads();               // prev MFMA A-reads done / stats ready
        {   // zero the alpha chunk
            float* afl = &Af[0][0][0];
            for (int it = t; it < 4 * 32 * 64; it += 256) afl[it] = 0.0f;
        }
        __syncthreads();
        // scatter alpha for edges whose src falls in this 64-wide chunk
        for (int nd = 0; nd < 8; ++nd) {
            const int rloc = w * 8 + nd;
            const int d = row0 + rloc;
            const int beg = rowp[d];
            const int deg = rowp[d + 1] - beg;
            const float edh  = edhL[rloc][h];
            const float vmax = vmL[rloc][h];
            const float inv  = invL[rloc][h];
            for (int i = ei; i < deg; i += 16) {
                const int srcn = esrc[beg + i];
                const int rel = srcn - gbase;
                if ((rel >> 6) == ck) {
                    const float a =
                        __expf(leaky02(es[srcn * HH + h] + edh) - vmax) * inv;
                    atomicAdd(&Af[h][rloc][rel & 63], a);
                }
            }
            if (ei == 0) {             // self-loop diagonal
                const int rel = rbase + rloc;
                if ((rel >> 6) == ck) atomicAdd(&Af[h][rloc][rel & 63], aslL[rloc][h]);
            }
        }
        __syncthreads();
        // MFMA: two K-steps of 32 within this chunk
#pragma unroll
        for (int ks = 0; ks < 2; ++ks) {
            short8 ah0, al0, ah1, al1;
            {
                unsigned short hh, ll;
#pragma unroll
                for (int j = 0; j < 8; ++j) {
                    split2(Af[w][m][ks * 32 + q * 8 + j], hh, ll);
                    ah0[j] = (short)hh; al0[j] = (short)ll;
                    split2(Af[w][16 + m][ks * 32 + q * 8 + j], hh, ll);
                    ah1[j] = (short)hh; al1[j] = (short)ll;
                }
            }
            const int kg = ck * 2 + ks;
#pragma unroll
            for (int c = 0; c < 4; ++c) {
                const int nt = (w << 2) + c;
                const size_t boff = gb2 + ((size_t)(nt * 16 + kg) * 64 + l) * 8;
                short8 bh = *(const short8*)(Bph + boff);
                short8 bl = *(const short8*)(Bpl + boff);
                acc0[c] = __builtin_amdgcn_mfma_f32_16x16x32_bf16(ah0, bh, acc0[c], 0, 0, 0);
                acc0[c] = __builtin_amdgcn_mfma_f32_16x16x32_bf16(ah0, bl, acc0[c], 0, 0, 0);
                acc0[c] = __builtin_amdgcn_mfma_f32_16x16x32_bf16(al0, bh, acc0[c], 0, 0, 0);
                acc1[c] = __builtin_amdgcn_mfma_f32_16x16x32_bf16(ah1, bh, acc1[c], 0, 0, 0);
                acc1[c] = __builtin_amdgcn_mfma_f32_16x16x32_bf16(ah1, bl, acc1[c], 0, 0, 0);
                acc1[c] = __builtin_amdgcn_mfma_f32_16x16x32_bf16(al1, bh, acc1[c], 0, 0, 0);
            }
        }
    }

    // ---- epilogue: bias + ELU + featH (fp16) ----
#pragma unroll
    for (int c = 0; c < 4; ++c) {
        const int col = ncol0 + c * 16 + m;
        const float bv = bias[col];
#pragma unroll
        for (int r = 0; r < 4; ++r) {
            float o0 = acc0[c][r] + bv;
            o0 = o0 > 0.0f ? o0 : __expf(o0) - 1.0f;
            acc0[c][r] = o0;
            featH[(size_t)(row0 + q * 4 + r) * CC + col] = f2h(o0);
            float o1 = acc1[c][r] + bv;
            o1 = o1 > 0.0f ? o1 : __expf(o1) - 1.0f;
            acc1[c][r] = o1;
            featH[(size_t)(row0 + 16 + q * 4 + r) * CC + col] = f2h(o1);
        }
    }
    // ---- fused sc1/sc2 reductions ----
    float s1v[4], s2v[4];
#pragma unroll
    for (int c = 0; c < 4; ++c) {
        s1v[c] = sw1[ncol0 + c * 16 + m];
        s2v[c] = w12[ncol0 + c * 16 + m];
    }
#pragma unroll
    for (int r = 0; r < 4; ++r) {
        float p10 = 0.f, p20 = 0.f, p11 = 0.f, p21 = 0.f;
#pragma unroll
        for (int c = 0; c < 4; ++c) {
            p10 = fmaf(acc0[c][r], s1v[c], p10);
            p20 = fmaf(acc0[c][r], s2v[c], p20);
            p11 = fmaf(acc1[c][r], s1v[c], p11);
            p21 = fmaf(acc1[c][r], s2v[c], p21);
        }
#pragma unroll
        for (int o = 8; o >= 1; o >>= 1) {
            p10 += __shfl_down(p10, o, 16);
            p20 += __shfl_down(p20, o, 16);
            p11 += __shfl_down(p11, o, 16);
            p21 += __shfl_down(p21, o, 16);
        }
        if (m == 0) {
            scp1[w][q * 4 + r] = p10;      scp2[w][q * 4 + r] = p20;
            scp1[w][16 + q * 4 + r] = p11; scp2[w][16 + q * 4 + r] = p21;
        }
    }
    __syncthreads();
    if (t < 32) {
        const float r1 = scp1[0][t] + scp1[1][t] + scp1[2][t] + scp1[3][t];
        const float r2 = scp2[0][t] + scp2[1][t] + scp2[2][t] + scp2[3][t];
        sc1[row0 + t] = r1 + sb1[0];
        sc2[row0 + t] = r2 + b12[0];
    }
}

// ---------------- pool: single-wave radix-select, 1 block/graph -----------
__global__ __launch_bounds__(512) void pool_g(const float* __restrict__ sc1,
                                              const float* __restrict__ sc2,
                                              const unsigned short* __restrict__ featH,
                                              const float* __restrict__ Wc,
                                              const float* __restrict__ bc,
                                              const float* __restrict__ c2w,
                                              const float* __restrict__ c2b,
                                              float* __restrict__ outp) {
    __shared__ unsigned int us[NPG];
    __shared__ unsigned char kb[NPG];
    __shared__ int list[KP2];
    __shared__ float v0[CC];
    __shared__ float vbuf[2][CC];
    __shared__ float part[4][64];
    __shared__ float v2[64];
    const int g = blockIdx.x;
    const int t = threadIdx.x;
    const int lane = t & 63, wid = t >> 6;

    const float s2val = sc2[(size_t)g * NPG + t];
    us[t] = fmap(sc1[(size_t)g * NPG + t]);
    __syncthreads();

    if (wid == 0) {
        unsigned int u[8];
#pragma unroll
        for (int j = 0; j < 8; ++j) u[j] = us[j * 64 + lane];
        unsigned int p = 0;
        for (int bb = 31; bb >= 0; --bb) {
            const unsigned int cand = p | (1u << bb);
            int cnt = 0;
#pragma unroll
            for (int j = 0; j < 8; ++j) cnt += __popcll(__ballot(u[j] >= cand));
            if (cnt >= KP1) p = cand;
        }
        int cgt = 0;
#pragma unroll
        for (int j = 0; j < 8; ++j) cgt += __popcll(__ballot(u[j] > p));
        const int kk = KP1 - cgt;
        const unsigned long long lm = (1ull << lane) - 1ull;
        int preEq = 0;
#pragma unroll
        for (int j = 0; j < 8; ++j) {
            const unsigned long long balEq = __ballot(u[j] == p);
            const int eqr = preEq + __popcll(balEq & lm);
            preEq += __popcll(balEq);
            kb[j * 64 + lane] =
                (unsigned char)((u[j] > p) || ((u[j] == p) && (eqr < kk)));
        }
    }
    __syncthreads();

    us[t] = kb[t] ? fmap(s2val) : 0u;
    __syncthreads();
    if (wid == 0) {
        unsigned int u[8];
#pragma unroll
        for (int j = 0; j < 8; ++j) u[j] = us[j * 64 + lane];
        unsigned int p = 0;
        for (int bb = 31; bb >= 0; --bb) {
            const unsigned int cand = p | (1u << bb);
            int cnt = 0;
#pragma unroll
            for (int j = 0; j < 8; ++j) cnt += __popcll(__ballot(u[j] >= cand));
            if (cnt >= KP2) p = cand;
        }
        int cgt = 0;
#pragma unroll
        for (int j = 0; j < 8; ++j) cgt += __popcll(__ballot(u[j] > p));
        const int kk = KP2 - cgt;
        const unsigned long long lm = (1ull << lane) - 1ull;
        int preEq = 0, preKeep = 0;
#pragma unroll
        for (int j = 0; j < 8; ++j) {
            const unsigned long long balEq = __ballot(u[j] == p);
            const int eqr = preEq + __popcll(balEq & lm);
            preEq += __popcll(balEq);
            const int keep = (u[j] > p) || ((u[j] == p) && (eqr < kk));
            const unsigned long long balK = __ballot(keep);
            const int pos = preKeep + __popcll(balK & lm);
            preKeep += __popcll(balK);
            if (keep) list[pos] = j * 64 + lane;
        }
    }
    __syncthreads();

    {
        const int col = t & (CC - 1);
        const int hf = t >> 8;
        float acc = 0.0f;
        for (int i = hf * 64; i < hf * 64 + 64; ++i)
            acc += h2f(featH[((size_t)g * NPG + list[i]) * CC + col]);
        vbuf[hf][col] = acc;
    }
    __syncthreads();
    if (t < CC) v0[t] = (vbuf[0][t] + vbuf[1][t]) * (1.0f / KP2);
    __syncthreads();

    if (t < 256) {
        const int q = t >> 6, cth = t & 63;
        float pr = 0.0f;
        for (int j = q * 64; j < q * 64 + 64; ++j)
            pr = fmaf(v0[j], Wc[j * 64 + cth], pr);
        part[q][cth] = pr;
    }
    __syncthreads();
    if (t < 64) {
        float u = bc[t];
#pragma unroll
        for (int q = 0; q < 4; ++q) u += part[q][t];
        v2[t] = fmaxf(u, 0.0f);
    }
    __syncthreads();
    if (t < 2) {
        float o = c2b[t];
        for (int j = 0; j < 64; ++j) o = fmaf(v2[j], c2w[j * 2 + t], o);
        part[0][t] = o;
    }
    __syncthreads();
    if (t == 0) {
        float a = part[0][0], bq = part[0][1];
        float mx = fmaxf(a, bq);
        float lse = mx + logf(expf(a - mx) + expf(bq - mx));
        outp[g * 2 + 0] = a - lse;
        outp[g * 2 + 1] = bq - lse;
    }
}

// ---------------- launcher ----------------
extern "C" void kernel_launch(void* const* d_in, const int* in_sizes, int n_in,
                              void* d_out, int out_size, void* d_ws, size_t ws_size,
                              hipStream_t stream) {
    const float* x      = (const float*)d_in[0];
    const int*   ei     = (const int*)d_in[1];
    const int*   src    = ei;
    const int*   dst    = ei + EG;
    const float* W1     = (const float*)d_in[3];
    const float* a_src1 = (const float*)d_in[4];
    const float* a_dst1 = (const float*)d_in[5];
    const float* b1     = (const float*)d_in[6];
    const float* W2     = (const float*)d_in[7];
    const float* a_src2 = (const float*)d_in[8];
    const float* a_dst2 = (const float*)d_in[9];
    const float* b2     = (const float*)d_in[10];
    const float* p1_sw  = (const float*)d_in[11];
    const float* p1_sb  = (const float*)d_in[12];
    const float* p1_tw  = (const float*)d_in[13];
    const float* p1_tb  = (const float*)d_in[14];
    const float* p2_sw  = (const float*)d_in[15];
    const float* p2_sb  = (const float*)d_in[16];
    const float* p2_tw  = (const float*)d_in[17];
    const float* p2_tb  = (const float*)d_in[18];
    const float* c1w    = (const float*)d_in[19];
    const float* c1b    = (const float*)d_in[20];
    const float* c2w    = (const float*)d_in[21];
    const float* c2b    = (const float*)d_in[22];
    float* out = (float*)d_out;

    // workspace layout
    float* ws = (float*)d_ws;
    float* z = ws;                                      // NN*CC floats region
    unsigned short* zh1   = (unsigned short*)z;         //   layer-1 fp16 rows
    unsigned short* zh2ph = zh1 + (size_t)NN * CC;      //   layer-2 packed hi
    float* fregion = z + (size_t)NN * CC;               // NN*CC floats
    unsigned short* featH = (unsigned short*)fregion;   //   layer-2 fp16 feat
    float* wsp = fregion + (size_t)NN * CC;
    unsigned short* w1ph = (unsigned short*)wsp;        // 256*128 packed
    unsigned short* w1pl = w1ph + 256 * FIN;
    unsigned short* w2ph = w1pl + 256 * FIN;            // 256*256 packed
    unsigned short* w2pl = w2ph + 256 * CC;
    float* es  = (float*)(w2pl + 256 * CC);             // N*H (layer 1)
    float* ed  = es + NN * HH;
    int* rowp  = (int*)(ed + NN * HH);                  // N+1
    int* esrc  = rowp + NN + 1;                         // E
    float* sc1 = (float*)(esrc + EG);                   // N
    float* sc2 = sc1 + NN;                              // N
    int* sel1  = (int*)(sc2 + NN);                      // N (layout kept)
    float* w12 = (float*)(sel1 + NN);                   // C
    float* b12 = w12 + CC;                              // 1 (padded 64)
    float* T   = b12 + 64;                              // 256*64
    float* Wc  = T + CC * 64;                           // 256*64
    float* bc2 = Wc + CC * 64;                          // 64
    float* bcv = bc2 + 64;                              // 64
    float* es2 = bcv + 64;                              // N*H (layer 2)
    float* ed2 = es2 + (size_t)NN * HH;                 // N*H
    unsigned short* xph = (unsigned short*)(ed2 + (size_t)NN * HH); // NN*FIN
    unsigned short* xpl = xph + (size_t)NN * FIN;                   // NN*FIN
    unsigned short* zh2pl = xpl + (size_t)NN * FIN;     // NN*CC packed lo

    // ---- fused setup: CSR + prep + W pack + x split-pack ----
    setup_k<<<BG + 66 + 48 + 512, 1024, 0, stream>>>(
        src, dst, rowp, esrc,
        p1_tw, p2_sw, p1_tb, p2_sb, w12, b12, p2_tw, c1w, p2_tb, T, bc2,
        W1, W2, w1ph, w1pl, w2ph, w2pl, x, xph, xpl);

    // ---- GAT layer 1 GEMM: packed A (+ fold_W riders) ----
    gemm_mfma_attn<<<NN / 32 + 65, 256, 0, stream>>>(
        xph, xpl, w1ph, w1pl, zh1, FIN, a_src1, a_dst1, es, ed,
        p1_tw, T, p1_tb, bc2, c1b, Wc, bcv);

    // ---- fused edge1 + gemm2 (zh2 out in fragment-packed split-bf16) ----
    edge1_gemm2<<<NN / 32, 256, 0, stream>>>(
        zh1, rowp, esrc, es, ed, b1,
        w2ph, w2pl, zh2ph, zh2pl, a_src2, a_dst2, es2, ed2);

    // ---- layer-2 edge stage as dense SpMM (matrix cores) ----
    spmm_edge2<<<NN / 32, 256, 0, stream>>>(
        rowp, esrc, es2, ed2, b2, zh2ph, zh2pl, featH,
        p1_sw, p1_sb, w12, b12, sc1, sc2);

    // ---- pooling + head: single-wave radix-select, one block per graph ----
    pool_g<<<BG, 512, 0, stream>>>(sc1, sc2, featH, Wc, bcv, c2w, c2b, out);
}

// Round 12
// 232.727 us; speedup vs baseline: 1.2868x; 1.2868x over previous
//
#include <hip/hip_runtime.h>
#include <hip/hip_bf16.h>
#include <hip/hip_fp16.h>
#include <math.h>

// ---------------- problem constants ----------------
constexpr int NN  = 32768;   // nodes
constexpr int BG  = 64;      // graphs
constexpr int NPG = 512;     // nodes per graph
constexpr int EG  = 524288;  // edges
constexpr int EPG = EG / BG; // 8192 edges per graph
constexpr int HH  = 4;       // heads
constexpr int FH  = 64;      // per-head dim
constexpr int CC  = 256;     // H*Fh
constexpr int FIN = 128;
constexpr int KP1 = 256;     // pool1 k
constexpr int KP2 = 128;     // pool2 k
constexpr int NS  = 4;       // register edge slots: fast path deg <= 64

typedef __attribute__((ext_vector_type(8))) short short8;  // 8 bf16 = 4 VGPRs
typedef __attribute__((ext_vector_type(4))) float f32x4;
typedef __attribute__((ext_vector_type(2))) float f32x2v;  // packed-fp32 pair

__device__ inline float leaky02(float v) { return v > 0.0f ? v : 0.2f * v; }

__device__ inline unsigned short f2bf(float v) {
    __hip_bfloat16 h = __float2bfloat16(v);
    return *(unsigned short*)&h;
}
__device__ inline float bf2f(unsigned short u) {
    __hip_bfloat16 h;
    *(unsigned short*)&h = u;
    return __bfloat162float(h);
}
__device__ inline void split2(float v, unsigned short& hi, unsigned short& lo) {
    hi = f2bf(v);
    lo = f2bf(v - bf2f(hi));
}
// split 8 consecutive floats into hi/lo bf16 fragments (A-operand order)
__device__ inline void split8(const float* p, short8& hi, short8& lo) {
    const float4 f0 = *(const float4*)p;
    const float4 f1 = *(const float4*)(p + 4);
    unsigned short h, l;
    split2(f0.x, h, l); hi[0] = (short)h; lo[0] = (short)l;
    split2(f0.y, h, l); hi[1] = (short)h; lo[1] = (short)l;
    split2(f0.z, h, l); hi[2] = (short)h; lo[2] = (short)l;
    split2(f0.w, h, l); hi[3] = (short)h; lo[3] = (short)l;
    split2(f1.x, h, l); hi[4] = (short)h; lo[4] = (short)l;
    split2(f1.y, h, l); hi[5] = (short)h; lo[5] = (short)l;
    split2(f1.z, h, l); hi[6] = (short)h; lo[6] = (short)l;
    split2(f1.w, h, l); hi[7] = (short)h; lo[7] = (short)l;
}

__device__ inline unsigned short f2h(float v) {
    __half h = __float2half(v);
    return *(unsigned short*)&h;
}
__device__ inline float h2f(unsigned short u) {
    __half h;
    *(unsigned short*)&h = u;
    return __half2float(h);
}

// monotone map: float ordering -> uint ordering (never returns 0 for non-NaN)
__device__ inline unsigned int fmap(float v) {
    unsigned int b = __float_as_uint(v);
    return (b & 0x80000000u) ? ~b : (b | 0x80000000u);
}

// accumulate a * row[0..7] (fp16) into 4 packed-f32 pairs (v_pk_fma_f32)
__device__ inline void acc8h(const unsigned short* p, float a, f32x2v* acc) {
    const uint4 u = *(const uint4*)p;
    const __half2* hp = (const __half2*)&u;
    f32x2v av; av[0] = a; av[1] = a;
#pragma unroll
    for (int i = 0; i < 4; ++i) {
        const float2 f = __half22float2(hp[i]);
        f32x2v fv; fv[0] = f.x; fv[1] = f.y;
        acc[i] = __builtin_elementwise_fma(fv, av, acc[i]);
    }
}

// ---------------- fused setup: csr_build + prep + W pack + x pack ---------
// blocks 0..63: per-graph CSR (1024 thr). pb=b-BG: pb<66 prep; pb 66..113
// W pack (256 thr); pb>=114 (512 blocks): x split-pack (1024 thr).
__global__ __launch_bounds__(1024) void setup_k(
        const int* __restrict__ src, const int* __restrict__ dst,
        int* __restrict__ rowp, int* __restrict__ esrc,
        const float* __restrict__ tw1, const float* __restrict__ sw2,
        const float* __restrict__ tb1, const float* __restrict__ sb2,
        float* __restrict__ w12, float* __restrict__ b12,
        const float* __restrict__ tw2, const float* __restrict__ c1w,
        const float* __restrict__ tb2, float* __restrict__ T,
        float* __restrict__ bc2,
        const float* __restrict__ W1, const float* __restrict__ W2,
        unsigned short* __restrict__ w1ph, unsigned short* __restrict__ w1pl,
        unsigned short* __restrict__ w2ph, unsigned short* __restrict__ w2pl,
        const float* __restrict__ x,
        unsigned short* __restrict__ xph, unsigned short* __restrict__ xpl) {
    __shared__ int lcnt[NPG];
    __shared__ int wsum[8];
    const int b = blockIdx.x;
    const int t = threadIdx.x;
    if (b < BG) {
        // ---- CSR build for graph b ----
        const int g = b;
        const int ebase = g * EPG;
        const int nbase = g * NPG;
        if (t < NPG) lcnt[t] = 0;
        __syncthreads();
        int ds[EPG / 1024];
#pragma unroll
        for (int j = 0; j < EPG / 1024; ++j) {
            ds[j] = dst[ebase + t + 1024 * j] - nbase;
            atomicAdd(&lcnt[ds[j]], 1);
        }
        __syncthreads();
        // wave-shfl exclusive scan of lcnt[0..511] (2 barriers total)
        int c = 0, sInc = 0;
        if (t < NPG) {
            c = lcnt[t];
            sInc = c;
#pragma unroll
            for (int o = 1; o < 64; o <<= 1) {
                int v = __shfl_up(sInc, o);
                if ((t & 63) >= o) sInc += v;
            }
            if ((t & 63) == 63) wsum[t >> 6] = sInc;
        }
        __syncthreads();
        if (t < 8) {
            int v = wsum[t];
            int s = v;
#pragma unroll
            for (int o = 1; o < 8; o <<= 1) {
                int u2 = __shfl_up(s, o, 8);
                if (t >= o) s += u2;
            }
            wsum[t] = s - v;   // exclusive wave offset
        }
        __syncthreads();
        if (t < NPG) {
            const int ex = sInc - c + wsum[t >> 6];
            rowp[nbase + t] = ebase + ex;
            lcnt[t] = ex;      // reuse as cursor
        }
        if (g == BG - 1 && t == 0) rowp[NN] = EG;
        __syncthreads();
#pragma unroll
        for (int j = 0; j < EPG / 1024; ++j) {
            int p = atomicAdd(&lcnt[ds[j]], 1);
            esrc[ebase + p] = src[ebase + t + 1024 * j];
        }
        return;
    }
    const int pb = b - BG;
    if (pb >= 114) {
        // ---- x split-pack: 512 blocks x 1024 thr x 8 elems ----
        const size_t idx = ((size_t)(pb - 114) * 1024 + t) * 8;
        short8 hi, lo;
        split8(x + idx, hi, lo);
        *(short8*)(xph + idx) = hi;
        *(short8*)(xpl + idx) = lo;
        return;
    }
    if (t >= 256) return;
    if (pb < 66) {
        // ---- prep ----
        if (pb == 0) {
            float s = 0.0f;
            for (int o = 0; o < CC; ++o) s += tw1[t * CC + o] * sw2[o];
            w12[t] = s;
            if (t == 0) {
                float bb = 0.0f;
                for (int o = 0; o < CC; ++o) bb += tb1[o] * sw2[o];
                *b12 = bb + sb2[0];
            }
        } else if (pb < 65) {
            const int r = (pb - 1) * 4 + (t >> 6);
            const int cth = t & 63;
            float s = 0.0f;
            for (int j = 0; j < CC; ++j) s = fmaf(tw2[r * CC + j], c1w[j * 64 + cth], s);
            T[r * 64 + cth] = s;
        } else if (t < 64) {
            float s = 0.0f;
            for (int j = 0; j < CC; ++j) s = fmaf(tb2[j], c1w[j * 64 + t], s);
            bc2[t] = s;
        }
    } else {
        // ---- W pack: [nt][kg][lane l][j]: n=nt*16+(l&15), k=kg*32+(l>>4)*8+j
        const int idx = (pb - 66) * 256 + t;   // 0..12287
        if (idx < 4096) {                      // W1: 16 nt x 4 kg x 64 l
            const int nt = idx >> 8, rem = idx & 255;
            const int kg = rem >> 6, l = rem & 63;
            const int n = nt * 16 + (l & 15);
            const int kb = kg * 32 + (l >> 4) * 8;
            unsigned short h[8], lo[8];
#pragma unroll
            for (int j = 0; j < 8; ++j) split2(W1[(kb + j) * CC + n], h[j], lo[j]);
#pragma unroll
            for (int j = 0; j < 8; ++j) {
                w1ph[(size_t)idx * 8 + j] = h[j];
                w1pl[(size_t)idx * 8 + j] = lo[j];
            }
        } else {                               // W2: 16 nt x 8 kg x 64 l
            const int i2 = idx - 4096;
            const int nt = i2 >> 9, rem = i2 & 511;
            const int kg = rem >> 6, l = rem & 63;
            const int n = nt * 16 + (l & 15);
            const int kb = kg * 32 + (l >> 4) * 8;
            unsigned short h[8], lo[8];
#pragma unroll
            for (int j = 0; j < 8; ++j) split2(W2[(kb + j) * CC + n], h[j], lo[j]);
#pragma unroll
            for (int j = 0; j < 8; ++j) {
                w2ph[(size_t)i2 * 8 + j] = h[j];
                w2pl[(size_t)i2 * 8 + j] = lo[j];
            }
        }
    }
}

// ---------------- MFMA GEMM (layer 1): A = packed split-bf16 pair ---------
// Extra blocks (bx >= NN/32) run fold_W: Wc = tw1@T, bcv = tb1@T + bc2 + c1b
__global__ __launch_bounds__(256, 4) void gemm_mfma_attn(
        const unsigned short* __restrict__ Ahi, const unsigned short* __restrict__ Alo,
        const unsigned short* __restrict__ Bph, const unsigned short* __restrict__ Bpl,
        unsigned short* __restrict__ Cb, int K,
        const float* __restrict__ a_src, const float* __restrict__ a_dst,
        float* __restrict__ es, float* __restrict__ ed,
        const float* __restrict__ tw1, const float* __restrict__ T,
        const float* __restrict__ tb1, const float* __restrict__ bc2,
        const float* __restrict__ c1b, float* __restrict__ Wc,
        float* __restrict__ bcv) {
    const int t = threadIdx.x;
    const int bx = blockIdx.x;
    if (bx >= NN / 32) {
        const int fb = bx - NN / 32;
        if (fb < 64) {
            const int r = fb * 4 + (t >> 6);
            const int cth = t & 63;
            float s = 0.0f;
            for (int j = 0; j < CC; ++j) s = fmaf(tw1[r * CC + j], T[j * 64 + cth], s);
            Wc[r * 64 + cth] = s;
        } else if (t < 64) {
            float s = 0.0f;
            for (int j = 0; j < CC; ++j) s = fmaf(tb1[j], T[j * 64 + t], s);
            bcv[t] = s + bc2[t] + c1b[t];
        }
        return;
    }
    const int w = t >> 6;          // wave = col strip = head
    const int l = t & 63;
    const int xcd  = bx & 7;
    const int slot = bx >> 3;                  // 0..127
    const int gph  = xcd + ((slot >> 4) << 3); // graph
    const int row0 = gph * NPG + ((slot & 15) << 5);
    const int m = l & 15;
    const int q = l >> 4;
    const int ncol0 = w * 64;
    const int KG = K >> 5;

    const unsigned short* aH0 = Ahi + (size_t)(row0 + m) * K + q * 8;
    const unsigned short* aL0 = Alo + (size_t)(row0 + m) * K + q * 8;
    const unsigned short* aH1 = aH0 + (size_t)16 * K;
    const unsigned short* aL1 = aL0 + (size_t)16 * K;

    f32x4 acc0[4], acc1[4];
#pragma unroll
    for (int c = 0; c < 4; ++c) {
        acc0[c] = (f32x4){0.f, 0.f, 0.f, 0.f};
        acc1[c] = (f32x4){0.f, 0.f, 0.f, 0.f};
    }

    for (int kg = 0; kg < KG; ++kg) {
        const int ko = kg * 32;
        short8 ah0 = *(const short8*)(aH0 + ko);
        short8 al0 = *(const short8*)(aL0 + ko);
        short8 ah1 = *(const short8*)(aH1 + ko);
        short8 al1 = *(const short8*)(aL1 + ko);
#pragma unroll
        for (int c = 0; c < 4; ++c) {
            const int nt = (w << 2) + c;
            const size_t boff = ((size_t)(nt * KG + kg) * 64 + l) * 8;
            short8 bh = *(const short8*)(Bph + boff);
            short8 bl = *(const short8*)(Bpl + boff);
            acc0[c] = __builtin_amdgcn_mfma_f32_16x16x32_bf16(ah0, bh, acc0[c], 0, 0, 0);
            acc0[c] = __builtin_amdgcn_mfma_f32_16x16x32_bf16(ah0, bl, acc0[c], 0, 0, 0);
            acc0[c] = __builtin_amdgcn_mfma_f32_16x16x32_bf16(al0, bh, acc0[c], 0, 0, 0);
            acc1[c] = __builtin_amdgcn_mfma_f32_16x16x32_bf16(ah1, bh, acc1[c], 0, 0, 0);
            acc1[c] = __builtin_amdgcn_mfma_f32_16x16x32_bf16(ah1, bl, acc1[c], 0, 0, 0);
            acc1[c] = __builtin_amdgcn_mfma_f32_16x16x32_bf16(al1, bh, acc1[c], 0, 0, 0);
        }
    }

#pragma unroll
    for (int c = 0; c < 4; ++c)
#pragma unroll
        for (int r = 0; r < 4; ++r) {
            Cb[(size_t)(row0 + q * 4 + r) * CC + ncol0 + c * 16 + m] = f2h(acc0[c][r]);
            Cb[(size_t)(row0 + 16 + q * 4 + r) * CC + ncol0 + c * 16 + m] = f2h(acc1[c][r]);
        }

    float asv[4], adv[4];
#pragma unroll
    for (int c = 0; c < 4; ++c) {
        asv[c] = a_src[ncol0 + c * 16 + m];
        adv[c] = a_dst[ncol0 + c * 16 + m];
    }
#pragma unroll
    for (int r = 0; r < 4; ++r) {
        float ps0 = 0.f, pd0 = 0.f, ps1 = 0.f, pd1 = 0.f;
#pragma unroll
        for (int c = 0; c < 4; ++c) {
            ps0 = fmaf(acc0[c][r], asv[c], ps0);
            pd0 = fmaf(acc0[c][r], adv[c], pd0);
            ps1 = fmaf(acc1[c][r], asv[c], ps1);
            pd1 = fmaf(acc1[c][r], adv[c], pd1);
        }
#pragma unroll
        for (int o = 8; o >= 1; o >>= 1) {
            ps0 += __shfl_down(ps0, o, 16);
            pd0 += __shfl_down(pd0, o, 16);
            ps1 += __shfl_down(ps1, o, 16);
            pd1 += __shfl_down(pd1, o, 16);
        }
        if (m == 0) {
            es[(row0 + q * 4 + r) * HH + w] = ps0;
            ed[(row0 + q * 4 + r) * HH + w] = pd0;
            es[(row0 + 16 + q * 4 + r) * HH + w] = ps1;
            ed[(row0 + 16 + q * 4 + r) * HH + w] = pd1;
        }
    }
}

// ---------------- fused edge1 + gemm2: one block = 32 nodes (R6 config) ---
__global__ __launch_bounds__(256) void edge1_gemm2(
        const unsigned short* __restrict__ zh1,
        const int* __restrict__ rowp, const int* __restrict__ esrc,
        const float* __restrict__ es1, const float* __restrict__ ed1,
        const float* __restrict__ bias,
        const unsigned short* __restrict__ Bph, const unsigned short* __restrict__ Bpl,
        unsigned short* __restrict__ zh2,
        const float* __restrict__ a_src, const float* __restrict__ a_dst,
        float* __restrict__ es2, float* __restrict__ ed2) {
    __shared__ unsigned char AhB[32 * 512];
    __shared__ unsigned char AlB[32 * 512];
    const int t = threadIdx.x;
    const int w = t >> 6;
    const int l = t & 63;
    const int bx   = blockIdx.x;               // 0..1023
    const int xcd  = bx & 7;
    const int slot = bx >> 3;
    const int gph  = xcd + ((slot >> 4) << 3);
    const int row0 = gph * NPG + ((slot & 15) << 5);

    // ---- phase A lane roles ----
    const int h    = l & 3;
    const int ei   = l >> 2;
    const int lh   = l & 31;
    const int half = l >> 5;
    const int hcol = lh >> 3;
    const int c0   = lh << 3;

    for (int nd = 0; nd < 8; ++nd) {
        const int rloc = w * 8 + nd;           // 0..31
        const int d = row0 + rloc;
        const int beg = rowp[d];
        const int deg = rowp[d + 1] - beg;

        f32x2v acc[4];
#pragma unroll
        for (int i = 0; i < 4; ++i) acc[i] = (f32x2v){0.f, 0.f};

        if (deg <= 16 * NS) {
            const float edh = ed1[d * HH + h];
            int   sidx[NS];
            float v[NS];
#pragma unroll
            for (int j = 0; j < NS; ++j) { sidx[j] = d; v[j] = 0.0f; }
            float vmax = -INFINITY, eself = 0.0f, vself = 0.0f;
            if (ei == 0) {
                vself = leaky02(es1[d * HH + h] + edh);
                vmax = vself;
            }
#pragma unroll
            for (int j = 0; j < NS; ++j) {
                int i = ei + 16 * j;
                if (i < deg) {
                    sidx[j] = esrc[beg + i];
                    v[j] = leaky02(es1[sidx[j] * HH + h] + edh);
                    vmax = fmaxf(vmax, v[j]);
                }
            }
#pragma unroll
            for (int o = 4; o <= 32; o <<= 1) vmax = fmaxf(vmax, __shfl_xor(vmax, o));
            float dsum = 0.0f;
#pragma unroll
            for (int j = 0; j < NS; ++j) {
                int i = ei + 16 * j;
                if (i < deg) { v[j] = __expf(v[j] - vmax); dsum += v[j]; }
            }
            if (ei == 0) { eself = __expf(vself - vmax); dsum += eself; }
#pragma unroll
            for (int o = 4; o <= 32; o <<= 1) dsum += __shfl_xor(dsum, o);
            const float inv = 1.0f / (dsum + 1e-16f);
#pragma unroll
            for (int j = 0; j < NS; ++j) v[j] *= inv;
            eself *= inv;

            float aself = __shfl(eself, hcol);
            if (half) aself = 0.0f;
            acc8h(zh1 + (size_t)d * CC + c0, aself, acc);

#pragma unroll
            for (int j = 0; j < NS; ++j) {
                if (16 * j < deg) {
#pragma unroll
                    for (int rr = 0; rr < 8; ++rr) {
                        if (16 * j + 2 * rr < deg) {
                            const int slb  = (2 * rr + half) << 2;
                            const int srcn = __shfl(sidx[j], slb);
                            const float a  = __shfl(v[j], slb + hcol);
                            acc8h(zh1 + (size_t)srcn * CC + c0, a, acc);
                        }
                    }
                }
            }
        } else {
            const float edh = ed1[d * HH + h];
            float vmax = (ei == 0) ? leaky02(es1[d * HH + h] + edh) : -INFINITY;
            for (int i = ei; i < deg; i += 16)
                vmax = fmaxf(vmax, leaky02(es1[esrc[beg + i] * HH + h] + edh));
#pragma unroll
            for (int o = 4; o <= 32; o <<= 1) vmax = fmaxf(vmax, __shfl_xor(vmax, o));
            float dsum = (ei == 0) ? __expf(leaky02(es1[d * HH + h] + edh) - vmax) : 0.0f;
            for (int i = ei; i < deg; i += 16)
                dsum += __expf(leaky02(es1[esrc[beg + i] * HH + h] + edh) - vmax);
#pragma unroll
            for (int o = 4; o <= 32; o <<= 1) dsum += __shfl_xor(dsum, o);
            const float inv = 1.0f / (dsum + 1e-16f);

            const float vmaxc = __shfl(vmax, hcol);
            const float invc  = __shfl(inv,  hcol);
            const float edh4  = ed1[d * HH + hcol];
            float a0 = __expf(leaky02(es1[d * HH + hcol] + edh4) - vmaxc) * invc;
            if (half) a0 = 0.0f;
            acc8h(zh1 + (size_t)d * CC + c0, a0, acc);
            for (int e = half; e < deg; e += 2) {
                const int srcn = esrc[beg + e];
                const float a = __expf(leaky02(es1[srcn * HH + hcol] + edh4) - vmaxc) * invc;
                acc8h(zh1 + (size_t)srcn * CC + c0, a, acc);
            }
        }

        // combine the two edge-halves
#pragma unroll
        for (int i = 0; i < 4; ++i) {
            float a0 = acc[i][0]; a0 += __shfl_xor(a0, 32);
            float a1 = acc[i][1]; a1 += __shfl_xor(a1, 32);
            acc[i][0] = a0; acc[i][1] = a1;
        }

        const int cw = c0 + (half << 2);
        float o0 = half ? acc[2][0] : acc[0][0];
        float o1 = half ? acc[2][1] : acc[0][1];
        float o2 = half ? acc[3][0] : acc[1][0];
        float o3 = half ? acc[3][1] : acc[1][1];

        const float4 bv = *(const float4*)(bias + cw);
        o0 += bv.x; o0 = o0 > 0.0f ? o0 : __expf(o0) - 1.0f;
        o1 += bv.y; o1 = o1 > 0.0f ? o1 : __expf(o1) - 1.0f;
        o2 += bv.z; o2 = o2 > 0.0f ? o2 : __expf(o2) - 1.0f;
        o3 += bv.w; o3 = o3 > 0.0f ? o3 : __expf(o3) - 1.0f;

        ushort4 uh, ul;
        split2(o0, uh.x, ul.x);
        split2(o1, uh.y, ul.y);
        split2(o2, uh.z, ul.z);
        split2(o3, uh.w, ul.w);
        const size_t bo = (size_t)(((rloc * 512) + cw * 2) ^ ((rloc & 7) << 4));
        *(ushort4*)(AhB + bo) = uh;
        *(ushort4*)(AlB + bo) = ul;
    }

    __syncthreads();

    // ---- phase B: 32x256 GEMM, K=256, A from swizzled LDS ----
    const int m = l & 15;
    const int q = l >> 4;
    const int ncol0 = w * 64;
    constexpr int KG = CC >> 5;   // 8

    f32x4 acc0[4], acc1[4];
#pragma unroll
    for (int c = 0; c < 4; ++c) {
        acc0[c] = (f32x4){0.f, 0.f, 0.f, 0.f};
        acc1[c] = (f32x4){0.f, 0.f, 0.f, 0.f};
    }

    for (int kg = 0; kg < KG; ++kg) {
        const int co = kg * 64 + q * 16;      // byte col offset
        const size_t bo0 = (size_t)(((m * 512) + co) ^ ((m & 7) << 4));
        const size_t bo1 = (size_t)((((16 + m) * 512) + co) ^ ((m & 7) << 4));
        short8 ah0 = *(const short8*)(AhB + bo0);
        short8 al0 = *(const short8*)(AlB + bo0);
        short8 ah1 = *(const short8*)(AhB + bo1);
        short8 al1 = *(const short8*)(AlB + bo1);
#pragma unroll
        for (int c = 0; c < 4; ++c) {
            const int nt = (w << 2) + c;
            const size_t boff = ((size_t)(nt * KG + kg) * 64 + l) * 8;
            short8 bh = *(const short8*)(Bph + boff);
            short8 bl = *(const short8*)(Bpl + boff);
            acc0[c] = __builtin_amdgcn_mfma_f32_16x16x32_bf16(ah0, bh, acc0[c], 0, 0, 0);
            acc0[c] = __builtin_amdgcn_mfma_f32_16x16x32_bf16(ah0, bl, acc0[c], 0, 0, 0);
            acc0[c] = __builtin_amdgcn_mfma_f32_16x16x32_bf16(al0, bh, acc0[c], 0, 0, 0);
            acc1[c] = __builtin_amdgcn_mfma_f32_16x16x32_bf16(ah1, bh, acc1[c], 0, 0, 0);
            acc1[c] = __builtin_amdgcn_mfma_f32_16x16x32_bf16(ah1, bl, acc1[c], 0, 0, 0);
            acc1[c] = __builtin_amdgcn_mfma_f32_16x16x32_bf16(al1, bh, acc1[c], 0, 0, 0);
        }
    }

#pragma unroll
    for (int c = 0; c < 4; ++c)
#pragma unroll
        for (int r = 0; r < 4; ++r) {
            zh2[(size_t)(row0 + q * 4 + r) * CC + ncol0 + c * 16 + m] = f2h(acc0[c][r]);
            zh2[(size_t)(row0 + 16 + q * 4 + r) * CC + ncol0 + c * 16 + m] = f2h(acc1[c][r]);
        }

    float asv[4], adv[4];
#pragma unroll
    for (int c = 0; c < 4; ++c) {
        asv[c] = a_src[ncol0 + c * 16 + m];
        adv[c] = a_dst[ncol0 + c * 16 + m];
    }
#pragma unroll
    for (int r = 0; r < 4; ++r) {
        float ps0 = 0.f, pd0 = 0.f, ps1 = 0.f, pd1 = 0.f;
#pragma unroll
        for (int c = 0; c < 4; ++c) {
            ps0 = fmaf(acc0[c][r], asv[c], ps0);
            pd0 = fmaf(acc0[c][r], adv[c], pd0);
            ps1 = fmaf(acc1[c][r], asv[c], ps1);
            pd1 = fmaf(acc1[c][r], adv[c], pd1);
        }
#pragma unroll
        for (int o = 8; o >= 1; o >>= 1) {
            ps0 += __shfl_down(ps0, o, 16);
            pd0 += __shfl_down(pd0, o, 16);
            ps1 += __shfl_down(ps1, o, 16);
            pd1 += __shfl_down(pd1, o, 16);
        }
        if (m == 0) {
            es2[(row0 + q * 4 + r) * HH + w] = ps0;
            ed2[(row0 + q * 4 + r) * HH + w] = pd0;
            es2[(row0 + 16 + q * 4 + r) * HH + w] = ps1;
            ed2[(row0 + 16 + q * 4 + r) * HH + w] = pd1;
        }
    }
}

// ---------------- GAT edge stage (layer 2): feat stored fp16 --------------
__global__ __launch_bounds__(256) void gat_edge(const unsigned short* __restrict__ zh,
                                                const int* __restrict__ rowp,
                                                const int* __restrict__ esrc,
                                                const float* __restrict__ es,
                                                const float* __restrict__ ed,
                                                const float* __restrict__ bias,
                                                unsigned short* __restrict__ featH,
                                                const float* __restrict__ sw1,
                                                const float* __restrict__ sb1,
                                                const float* __restrict__ w12,
                                                const float* __restrict__ b12,
                                                float* __restrict__ sc1,
                                                float* __restrict__ sc2) {
    const int w = threadIdx.x >> 6;
    const int l = threadIdx.x & 63;
    const int b    = blockIdx.x;              // 0..8191
    const int xcd  = b & 7;
    const int slot = b >> 3;                  // 0..1023
    const int gph  = xcd + ((slot >> 7) << 3);
    const int d    = gph * NPG + ((slot & 127) << 2) + w;

    const int h    = l & 3;
    const int ei   = l >> 2;
    const int lh   = l & 31;
    const int half = l >> 5;
    const int hcol = lh >> 3;
    const int c0   = lh << 3;

    const int beg = rowp[d];
    const int deg = rowp[d + 1] - beg;

    f32x2v acc[4];
#pragma unroll
    for (int i = 0; i < 4; ++i) acc[i] = (f32x2v){0.f, 0.f};

    if (deg <= 16 * NS) {
        const float edh = ed[d * HH + h];
        int   sidx[NS];
        float v[NS];
#pragma unroll
        for (int j = 0; j < NS; ++j) { sidx[j] = d; v[j] = 0.0f; }
        float vmax = -INFINITY, eself = 0.0f, vself = 0.0f;
        if (ei == 0) {
            vself = leaky02(es[d * HH + h] + edh);
            vmax = vself;
        }
#pragma unroll
        for (int j = 0; j < NS; ++j) {
            int i = ei + 16 * j;
            if (i < deg) {
                sidx[j] = esrc[beg + i];
                v[j] = leaky02(es[sidx[j] * HH + h] + edh);
                vmax = fmaxf(vmax, v[j]);
            }
        }
#pragma unroll
        for (int o = 4; o <= 32; o <<= 1) vmax = fmaxf(vmax, __shfl_xor(vmax, o));
        float dsum = 0.0f;
#pragma unroll
        for (int j = 0; j < NS; ++j) {
            int i = ei + 16 * j;
            if (i < deg) { v[j] = __expf(v[j] - vmax); dsum += v[j]; }
        }
        if (ei == 0) { eself = __expf(vself - vmax); dsum += eself; }
#pragma unroll
        for (int o = 4; o <= 32; o <<= 1) dsum += __shfl_xor(dsum, o);
        const float inv = 1.0f / (dsum + 1e-16f);
#pragma unroll
        for (int j = 0; j < NS; ++j) v[j] *= inv;
        eself *= inv;

        float aself = __shfl(eself, hcol);
        if (half) aself = 0.0f;
        acc8h(zh + (size_t)d * CC + c0, aself, acc);

#pragma unroll
        for (int j = 0; j < NS; ++j) {
            if (16 * j < deg) {
#pragma unroll
                for (int rr = 0; rr < 8; ++rr) {
                    if (16 * j + 2 * rr < deg) {
                        const int slb  = (2 * rr + half) << 2;
                        const int srcn = __shfl(sidx[j], slb);
                        const float a  = __shfl(v[j], slb + hcol);
                        acc8h(zh + (size_t)srcn * CC + c0, a, acc);
                    }
                }
            }
        }
    } else {
        const float edh = ed[d * HH + h];
        float vmax = (ei == 0) ? leaky02(es[d * HH + h] + edh) : -INFINITY;
        for (int i = ei; i < deg; i += 16)
            vmax = fmaxf(vmax, leaky02(es[esrc[beg + i] * HH + h] + edh));
#pragma unroll
        for (int o = 4; o <= 32; o <<= 1) vmax = fmaxf(vmax, __shfl_xor(vmax, o));
        float dsum = (ei == 0) ? __expf(leaky02(es[d * HH + h] + edh) - vmax) : 0.0f;
        for (int i = ei; i < deg; i += 16)
            dsum += __expf(leaky02(es[esrc[beg + i] * HH + h] + edh) - vmax);
#pragma unroll
        for (int o = 4; o <= 32; o <<= 1) dsum += __shfl_xor(dsum, o);
        const float inv = 1.0f / (dsum + 1e-16f);

        const float vmaxc = __shfl(vmax, hcol);
        const float invc  = __shfl(inv,  hcol);
        const float edh4  = ed[d * HH + hcol];
        float a0 = __expf(leaky02(es[d * HH + hcol] + edh4) - vmaxc) * invc;
        if (half) a0 = 0.0f;
        acc8h(zh + (size_t)d * CC + c0, a0, acc);
        for (int e = half; e < deg; e += 2) {
            const int srcn = esrc[beg + e];
            const float a = __expf(leaky02(es[srcn * HH + hcol] + edh4) - vmaxc) * invc;
            acc8h(zh + (size_t)srcn * CC + c0, a, acc);
        }
    }

#pragma unroll
    for (int i = 0; i < 4; ++i) {
        float a0 = acc[i][0]; a0 += __shfl_xor(a0, 32);
        float a1 = acc[i][1]; a1 += __shfl_xor(a1, 32);
        acc[i][0] = a0; acc[i][1] = a1;
    }

    const int cw = c0 + (half << 2);
    float o0 = half ? acc[2][0] : acc[0][0];
    float o1 = half ? acc[2][1] : acc[0][1];
    float o2 = half ? acc[3][0] : acc[1][0];
    float o3 = half ? acc[3][1] : acc[1][1];

    const float4 bv = *(const float4*)(bias + cw);
    o0 += bv.x; o0 = o0 > 0.0f ? o0 : __expf(o0) - 1.0f;
    o1 += bv.y; o1 = o1 > 0.0f ? o1 : __expf(o1) - 1.0f;
    o2 += bv.z; o2 = o2 > 0.0f ? o2 : __expf(o2) - 1.0f;
    o3 += bv.w; o3 = o3 > 0.0f ? o3 : __expf(o3) - 1.0f;

    {   // feat row stored fp16 (halves write + later pool read traffic)
        ushort4 uf;
        uf.x = f2h(o0); uf.y = f2h(o1); uf.z = f2h(o2); uf.w = f2h(o3);
        *(ushort4*)(featH + (size_t)d * CC + cw) = uf;
    }

    {
        const float4 s1 = *(const float4*)(sw1 + cw);
        const float4 s2 = *(const float4*)(w12 + cw);
        float r1 = o0 * s1.x + o1 * s1.y + o2 * s1.z + o3 * s1.w;
        float r2 = o0 * s2.x + o1 * s2.y + o2 * s2.z + o3 * s2.w;
#pragma unroll
        for (int off = 32; off >= 1; off >>= 1) {
            r1 += __shfl_xor(r1, off);
            r2 += __shfl_xor(r2, off);
        }
        if (l == 0) {
            sc1[d] = r1 + sb1[0];
            sc2[d] = r2 + b12[0];
        }
    }
}

// ---------------- pool: single-wave radix-select, 1 block/graph -----------
__global__ __launch_bounds__(512) void pool_g(const float* __restrict__ sc1,
                                              const float* __restrict__ sc2,
                                              const unsigned short* __restrict__ featH,
                                              const float* __restrict__ Wc,
                                              const float* __restrict__ bc,
                                              const float* __restrict__ c2w,
                                              const float* __restrict__ c2b,
                                              float* __restrict__ outp) {
    __shared__ unsigned int us[NPG];
    __shared__ unsigned char kb[NPG];
    __shared__ int list[KP2];
    __shared__ float v0[CC];
    __shared__ float vbuf[2][CC];
    __shared__ float part[4][64];
    __shared__ float v2[64];
    const int g = blockIdx.x;
    const int t = threadIdx.x;          // 0..511 = node within graph
    const int lane = t & 63, wid = t >> 6;

    const float s2val = sc2[(size_t)g * NPG + t];
    us[t] = fmap(sc1[(size_t)g * NPG + t]);
    __syncthreads();

    // ---- stage 1: top-KP1 of sc1, computed entirely in wave 0 ----
    if (wid == 0) {
        unsigned int u[8];
#pragma unroll
        for (int j = 0; j < 8; ++j) u[j] = us[j * 64 + lane];
        unsigned int p = 0;
        for (int bb = 31; bb >= 0; --bb) {
            const unsigned int cand = p | (1u << bb);
            int cnt = 0;
#pragma unroll
            for (int j = 0; j < 8; ++j) cnt += __popcll(__ballot(u[j] >= cand));
            if (cnt >= KP1) p = cand;
        }
        int cgt = 0;
#pragma unroll
        for (int j = 0; j < 8; ++j) cgt += __popcll(__ballot(u[j] > p));
        const int kk = KP1 - cgt;
        const unsigned long long lm = (1ull << lane) - 1ull;
        int preEq = 0;
#pragma unroll
        for (int j = 0; j < 8; ++j) {
            const unsigned long long balEq = __ballot(u[j] == p);
            const int eqr = preEq + __popcll(balEq & lm);
            preEq += __popcll(balEq);
            kb[j * 64 + lane] =
                (unsigned char)((u[j] > p) || ((u[j] == p) && (eqr < kk)));
        }
    }
    __syncthreads();

    // ---- stage 2: top-KP2 of masked sc2 (sentinel 0 never selected) ----
    us[t] = kb[t] ? fmap(s2val) : 0u;
    __syncthreads();
    if (wid == 0) {
        unsigned int u[8];
#pragma unroll
        for (int j = 0; j < 8; ++j) u[j] = us[j * 64 + lane];
        unsigned int p = 0;
        for (int bb = 31; bb >= 0; --bb) {
            const unsigned int cand = p | (1u << bb);
            int cnt = 0;
#pragma unroll
            for (int j = 0; j < 8; ++j) cnt += __popcll(__ballot(u[j] >= cand));
            if (cnt >= KP2) p = cand;
        }
        int cgt = 0;
#pragma unroll
        for (int j = 0; j < 8; ++j) cgt += __popcll(__ballot(u[j] > p));
        const int kk = KP2 - cgt;
        const unsigned long long lm = (1ull << lane) - 1ull;
        int preEq = 0, preKeep = 0;
#pragma unroll
        for (int j = 0; j < 8; ++j) {
            const unsigned long long balEq = __ballot(u[j] == p);
            const int eqr = preEq + __popcll(balEq & lm);
            preEq += __popcll(balEq);
            const int keep = (u[j] > p) || ((u[j] == p) && (eqr < kk));
            const unsigned long long balK = __ballot(keep);
            const int pos = preKeep + __popcll(balK & lm);
            preKeep += __popcll(balK);
            if (keep) list[pos] = j * 64 + lane;
        }
    }
    __syncthreads();

    // ---- mean over KP2 kept rows (fp16 feat, coalesced row reads) ----
    {
        const int col = t & (CC - 1);
        const int hf = t >> 8;             // 0/1
        float acc = 0.0f;
        for (int i = hf * 64; i < hf * 64 + 64; ++i)
            acc += h2f(featH[((size_t)g * NPG + list[i]) * CC + col]);
        vbuf[hf][col] = acc;
    }
    __syncthreads();
    if (t < CC) v0[t] = (vbuf[0][t] + vbuf[1][t]) * (1.0f / KP2);
    __syncthreads();

    // ---- head: relu(mean@Wc+bc)@c2w+c2b -> log_softmax ----
    if (t < 256) {
        const int q = t >> 6, cth = t & 63;
        float pr = 0.0f;
        for (int j = q * 64; j < q * 64 + 64; ++j)
            pr = fmaf(v0[j], Wc[j * 64 + cth], pr);
        part[q][cth] = pr;
    }
    __syncthreads();
    if (t < 64) {
        float u = bc[t];
#pragma unroll
        for (int q = 0; q < 4; ++q) u += part[q][t];
        v2[t] = fmaxf(u, 0.0f);
    }
    __syncthreads();
    if (t < 2) {
        float o = c2b[t];
        for (int j = 0; j < 64; ++j) o = fmaf(v2[j], c2w[j * 2 + t], o);
        part[0][t] = o;
    }
    __syncthreads();
    if (t == 0) {
        float a = part[0][0], bq = part[0][1];
        float mx = fmaxf(a, bq);
        float lse = mx + logf(expf(a - mx) + expf(bq - mx));
        outp[g * 2 + 0] = a - lse;
        outp[g * 2 + 1] = bq - lse;
    }
}

// ---------------- launcher ----------------
extern "C" void kernel_launch(void* const* d_in, const int* in_sizes, int n_in,
                              void* d_out, int out_size, void* d_ws, size_t ws_size,
                              hipStream_t stream) {
    const float* x      = (const float*)d_in[0];
    const int*   ei     = (const int*)d_in[1];
    const int*   src    = ei;
    const int*   dst    = ei + EG;
    const float* W1     = (const float*)d_in[3];
    const float* a_src1 = (const float*)d_in[4];
    const float* a_dst1 = (const float*)d_in[5];
    const float* b1     = (const float*)d_in[6];
    const float* W2     = (const float*)d_in[7];
    const float* a_src2 = (const float*)d_in[8];
    const float* a_dst2 = (const float*)d_in[9];
    const float* b2     = (const float*)d_in[10];
    const float* p1_sw  = (const float*)d_in[11];
    const float* p1_sb  = (const float*)d_in[12];
    const float* p1_tw  = (const float*)d_in[13];
    const float* p1_tb  = (const float*)d_in[14];
    const float* p2_sw  = (const float*)d_in[15];
    const float* p2_sb  = (const float*)d_in[16];
    const float* p2_tw  = (const float*)d_in[17];
    const float* p2_tb  = (const float*)d_in[18];
    const float* c1w    = (const float*)d_in[19];
    const float* c1b    = (const float*)d_in[20];
    const float* c2w    = (const float*)d_in[21];
    const float* c2b    = (const float*)d_in[22];
    float* out = (float*)d_out;

    // workspace layout
    float* ws = (float*)d_ws;
    float* z = ws;                                      // NN*CC floats region
    unsigned short* zh1 = (unsigned short*)z;           //   layer-1 fp16 rows
    unsigned short* zh2 = zh1 + (size_t)NN * CC;        //   layer-2 fp16 rows
    float* fregion = z + (size_t)NN * CC;               // NN*CC floats
    unsigned short* featH = (unsigned short*)fregion;   //   layer-2 fp16 feat
    float* wsp = fregion + (size_t)NN * CC;
    unsigned short* w1ph = (unsigned short*)wsp;        // 256*128 packed
    unsigned short* w1pl = w1ph + 256 * FIN;
    unsigned short* w2ph = w1pl + 256 * FIN;            // 256*256 packed
    unsigned short* w2pl = w2ph + 256 * CC;
    float* es  = (float*)(w2pl + 256 * CC);             // N*H (layer 1)
    float* ed  = es + NN * HH;
    int* rowp  = (int*)(ed + NN * HH);                  // N+1
    int* esrc  = rowp + NN + 1;                         // E
    float* sc1 = (float*)(esrc + EG);                   // N
    float* sc2 = sc1 + NN;                              // N
    int* sel1  = (int*)(sc2 + NN);                      // N (layout kept)
    float* w12 = (float*)(sel1 + NN);                   // C
    float* b12 = w12 + CC;                              // 1 (padded 64)
    float* T   = b12 + 64;                              // 256*64
    float* Wc  = T + CC * 64;                           // 256*64
    float* bc2 = Wc + CC * 64;                          // 64
    float* bcv = bc2 + 64;                              // 64
    float* es2 = bcv + 64;                              // N*H (layer 2)
    float* ed2 = es2 + (size_t)NN * HH;                 // N*H
    unsigned short* xph = (unsigned short*)(ed2 + (size_t)NN * HH); // NN*FIN
    unsigned short* xpl = xph + (size_t)NN * FIN;                   // NN*FIN

    // ---- fused setup: CSR + prep + W pack + x split-pack ----
    setup_k<<<BG + 66 + 48 + 512, 1024, 0, stream>>>(
        src, dst, rowp, esrc,
        p1_tw, p2_sw, p1_tb, p2_sb, w12, b12, p2_tw, c1w, p2_tb, T, bc2,
        W1, W2, w1ph, w1pl, w2ph, w2pl, x, xph, xpl);

    // ---- GAT layer 1 GEMM: packed A (+ fold_W riders) ----
    gemm_mfma_attn<<<NN / 32 + 65, 256, 0, stream>>>(
        xph, xpl, w1ph, w1pl, zh1, FIN, a_src1, a_dst1, es, ed,
        p1_tw, T, p1_tb, bc2, c1b, Wc, bcv);

    // ---- fused edge1 + gemm2 ----
    edge1_gemm2<<<NN / 32, 256, 0, stream>>>(
        zh1, rowp, esrc, es, ed, b1,
        w2ph, w2pl, zh2, a_src2, a_dst2, es2, ed2);

    // ---- GAT layer 2 edge stage (fp16 feat out) ----
    gat_edge<<<NN / 4, 256, 0, stream>>>(zh2, rowp, esrc, es2, ed2, b2,
                                         featH, p1_sw, p1_sb, w12, b12,
                                         sc1, sc2);

    // ---- pooling + head: single-wave radix-select, one block per graph ----
    pool_g<<<BG, 512, 0, stream>>>(sc1, sc2, featH, Wc, bcv, c2w, c2b, out);
}